// Round 2
// baseline (696.569 us; speedup 1.0000x reference)
//
#include <hip/hip_runtime.h>
#include <hip/hip_bf16.h>
#include <cstdint>
#include <cstddef>

// Problem shape (fixed by reference): B=8, N=1024, D=768, H=12, dh=64, 3 branches
#define B_   8
#define N_   1024
#define D_   768
#define H_   12
#define DH_  64
#define M_   (B_ * N_)          // 8192 rows
#define WSZ_ (D_ * D_)          // 589824 per weight matrix

typedef __bf16 bf16;
typedef bf16  bf16x8  __attribute__((ext_vector_type(8)));
typedef bf16  bf16x4  __attribute__((ext_vector_type(4)));
typedef float floatx4 __attribute__((ext_vector_type(4)));

// ---------------------------------------------------------------------------
// async global->LDS, 16B per lane (wave-uniform LDS base + lane*16)
__device__ __forceinline__ void gload_lds16(const void* g, void* l) {
    __builtin_amdgcn_global_load_lds(
        (const __attribute__((address_space(1))) unsigned int*)g,
        (__attribute__((address_space(3))) unsigned int*)l, 16, 0, 0);
}

// ---------------------------------------------------------------------------
// Kernel 1: per-row norm -> branch scales; x -> bf16.
__global__ __launch_bounds__(256) void prep_x(const float* __restrict__ x,
                                              bf16* __restrict__ xbf,
                                              float* __restrict__ sc /* [2][M_] */) {
    int row = blockIdx.x;
    int tid = threadIdx.x;
    const float* xr = x + (size_t)row * D_;
    bf16* xo = xbf + (size_t)row * D_;
    float v0 = xr[tid], v1 = xr[tid + 256], v2 = xr[tid + 512];
    xo[tid]       = (bf16)v0;
    xo[tid + 256] = (bf16)v1;
    xo[tid + 512] = (bf16)v2;
    float ss = v0 * v0 + v1 * v1 + v2 * v2;
    for (int off = 32; off; off >>= 1) ss += __shfl_xor(ss, off, 64);
    __shared__ float red[4];
    if ((tid & 63) == 0) red[tid >> 6] = ss;
    __syncthreads();
    if (tid == 0) {
        float t2 = red[0] + red[1] + red[2] + red[3];
        float t  = sqrtf(t2);                       // true ||x||
        const float scst = 0.31622776601683794f;    // sqrt(0.1)
        float un = fmaxf(t, 1e-5f);
        float s1 = tanhf(scst * un) / (scst * un);  // expmap0 scale
        float nh = fmaxf(t * s1, 1e-5f);            // project
        float maxnorm = (1.0f - 4e-3f) / scst;
        float sh = (nh > maxnorm) ? s1 * (maxnorm / nh) : s1;
        float arg = fminf(scst * un, 1.0f - 1e-5f); // logmap0 scale
        float artanh = 0.5f * logf((1.0f + arg) / (1.0f - arg));
        float ssc = artanh / (un * scst);
        sc[row]      = sh;
        sc[M_ + row] = ssc;
    }
}

// ---------------------------------------------------------------------------
// Kernel 2: weights fp32 -> bf16, layout wbf[branch][t][o][k], t: 0=q,1=k,2=v
__global__ __launch_bounds__(256) void prep_w(const float* __restrict__ wq,
                                              const float* __restrict__ wk,
                                              const float* __restrict__ wv,
                                              bf16* __restrict__ wbf) {
    size_t i = ((size_t)blockIdx.x * 256 + threadIdx.x) * 4;  // 9*WSZ_ total
    int z = (int)(i / WSZ_);
    int r = (int)(i % WSZ_);
    int branch = z / 3, t = z % 3;
    const float* src = (t == 0 ? wq : t == 1 ? wk : wv) + (size_t)branch * WSZ_ + r;
    float4 f = *(const float4*)src;
    bf16x4 o = { (bf16)f.x, (bf16)f.y, (bf16)f.z, (bf16)f.w };
    *(bf16x4*)(wbf + i) = o;
}

// ---------------------------------------------------------------------------
// Kernel 3: Y = x @ W^T, epilogue y = (s_branch[row]*y + bias[col]) * qscale
// q (t==0) additionally scaled by log2(e) so attention softmax can use exp2.
#define BM 128
#define BN 128
#define BK 32
__global__ __launch_bounds__(256) void gemm_qkv(
        const bf16* __restrict__ xbf, const bf16* __restrict__ wbf_all,
        const float* __restrict__ bq, const float* __restrict__ bk,
        const float* __restrict__ bv, const float* __restrict__ sc,
        int branch, bf16* __restrict__ qkv) {
    int t = blockIdx.z;
    const bf16*  wsrc = wbf_all + (size_t)(branch * 3 + t) * WSZ_;
    const float* bias = (t == 0 ? bq : t == 1 ? bk : bv) + branch * D_;
    bf16* out = qkv + (size_t)t * M_ * D_;
    int bm0 = blockIdx.y * BM;
    int bn0 = blockIdx.x * BN;

    __shared__ bf16 lA[BM * BK];   // 8 KB
    __shared__ bf16 lB[BN * BK];   // 8 KB

    int tid = threadIdx.x;
    int w = tid >> 6, lane = tid & 63;
    int wr = w >> 1, wc = w & 1;
    int quad = lane >> 4, c15 = lane & 15;
    int lrow = lane >> 2;           // 0..15 within a 16-row chunk
    int lcol = (lane & 3) * 8;      // k offset 0/8/16/24

    floatx4 acc[4][4];
    for (int i = 0; i < 4; i++)
        for (int j = 0; j < 4; j++)
            acc[i][j] = (floatx4){0.f, 0.f, 0.f, 0.f};

    for (int k0 = 0; k0 < D_; k0 += BK) {
        const bf16* ga = xbf  + ((size_t)(bm0 + w * 32 + lrow) * D_ + k0 + lcol);
        const bf16* gb = wsrc + ((size_t)(bn0 + w * 32 + lrow) * D_ + k0 + lcol);
        gload_lds16(ga,           (char*)lA + w * 2048);
        gload_lds16(ga + 16 * D_, (char*)lA + w * 2048 + 1024);
        gload_lds16(gb,           (char*)lB + w * 2048);
        gload_lds16(gb + 16 * D_, (char*)lB + w * 2048 + 1024);
        __syncthreads();

        int arow = wr * 64 + c15;
        int brow = wc * 64 + c15;
        int kq = quad * 8;
        bf16x8 af[4], bfm[4];
        for (int i = 0; i < 4; i++) af[i]  = *(const bf16x8*)(lA + (arow + i * 16) * BK + kq);
        for (int j = 0; j < 4; j++) bfm[j] = *(const bf16x8*)(lB + (brow + j * 16) * BK + kq);
        for (int i = 0; i < 4; i++)
            for (int j = 0; j < 4; j++)
                acc[i][j] = __builtin_amdgcn_mfma_f32_16x16x32_bf16(af[i], bfm[j], acc[i][j], 0, 0, 0);
        __syncthreads();
    }

    // epilogue: y = (s[row]*y + bias[col]) * qs
    const float* scb = (branch == 0) ? nullptr : sc + (size_t)(branch - 1) * M_;
    float qs = (t == 0) ? 1.4426950408889634f : 1.0f;   // log2(e) folded into q
    float bj[4];
    for (int j = 0; j < 4; j++) bj[j] = bias[bn0 + wc * 64 + j * 16 + c15];
    for (int i = 0; i < 4; i++) {
        int gRow0 = bm0 + wr * 64 + i * 16 + quad * 4;
        for (int r = 0; r < 4; r++) {
            float s = scb ? scb[gRow0 + r] : 1.0f;
            bf16* orow = out + (size_t)(gRow0 + r) * D_;
            for (int j = 0; j < 4; j++) {
                int gCol = bn0 + wc * 64 + j * 16 + c15;
                orow[gCol] = (bf16)((s * acc[i][j][r] + bj[j]) * qs);
            }
        }
    }
}

// ---------------------------------------------------------------------------
// Kernel 4: flash attention (no-max softmax: logits provably < 30 in log2
// domain, exp2 overflow at 128 -> clamp 120 is pure insurance).
// Block = 128 q-rows x (batch,head). 4 waves, each 32 q-rows (2 groups of 16).
// LDS stride 74 bf16 = 37 words == 5 (mod 32) -> <=2-way bank aliasing (free).
#define LDK 74
__global__ __launch_bounds__(256) void attn(const bf16* __restrict__ qkv,
                                            float* __restrict__ out,
                                            int accumulate) {
    int qt = blockIdx.x;              // 0..7
    int bh = blockIdx.y;              // 0..95
    int batch = bh / H_, head = bh % H_;
    int n0 = qt * 128;
    int tid = threadIdx.x, w = tid >> 6, lane = tid & 63;
    int quad = lane >> 4, c15 = lane & 15;

    const bf16* qb = qkv;
    const bf16* kb = qkv + (size_t)M_ * D_;
    const bf16* vb = qkv + (size_t)2 * M_ * D_;
    size_t baseRow = (size_t)batch * N_;
    int colOff = head * DH_;

    __shared__ bf16 sK[64 * LDK];        // K tile [key][d]        9472 B
    __shared__ bf16 sVt[64 * LDK];       // V tile transposed [d][key] 9472 B
    __shared__ bf16 sP[4][32 * LDK];     // per-wave P [q][key]   18944 B

    // Q A-fragments for 2 row-groups, held in registers for the whole block
    bf16x8 aq[2][2];
    for (int i = 0; i < 2; i++) {
        const bf16* qp = qb + ((baseRow + n0 + w * 32 + i * 16 + c15) * D_ + colOff + quad * 8);
        aq[i][0] = *(const bf16x8*)qp;
        aq[i][1] = *(const bf16x8*)(qp + 32);
    }

    float lsum[2][4];
    floatx4 o_acc[2][4];
    for (int i = 0; i < 2; i++)
        for (int r = 0; r < 4; r++) lsum[i][r] = 0.f;
    for (int i = 0; i < 2; i++)
        for (int j = 0; j < 4; j++) o_acc[i][j] = (floatx4){0.f, 0.f, 0.f, 0.f};

    // staging assignments (fixed per thread)
    int kkey = tid >> 3;                 // 0..31 (K rows, +32 for 2nd chunk)
    int kcol = (tid & 7) << 3;
    const bf16* kptr = kb + (baseRow + kkey) * D_ + colOff + kcol;
    int vkey = tid >> 2;                 // 0..63 (V rows)
    int vd0  = (tid & 3) << 4;           // d block 0/16/32/48
    int kodd = vkey & 1;
    int keyLow = vkey & ~1;
    const bf16* vptr = vb + (baseRow + vkey) * D_ + colOff + vd0;

    for (int kt = 0; kt < 16; kt++) {
        // --- stage K [64][64] row-major, vector 16B ---
        *(bf16x8*)(sK + kkey * LDK + kcol)        = *(const bf16x8*)kptr;
        *(bf16x8*)(sK + (kkey + 32) * LDK + kcol) = *(const bf16x8*)(kptr + 32 * D_);

        // --- stage V transposed via pair-exchange (4 shfl + 8 b32 writes) ---
        {
            union { bf16x8 v; uint32_t d[4]; } u0, u1;
            u0.v = *(const bf16x8*)vptr;         // d elems 0..7
            u1.v = *(const bf16x8*)(vptr + 8);   // d elems 8..15
            // even-key lane needs partner's elems 0..7; odd needs elems 8..15
            uint32_t send0 = kodd ? u0.d[0] : u1.d[0];
            uint32_t send1 = kodd ? u0.d[1] : u1.d[1];
            uint32_t send2 = kodd ? u0.d[2] : u1.d[2];
            uint32_t send3 = kodd ? u0.d[3] : u1.d[3];
            uint32_t recv[4];
            recv[0] = __shfl_xor((int)send0, 4, 64);
            recv[1] = __shfl_xor((int)send1, 4, 64);
            recv[2] = __shfl_xor((int)send2, 4, 64);
            recv[3] = __shfl_xor((int)send3, 4, 64);
            uint32_t mine[4];
            for (int t = 0; t < 4; t++) mine[t] = kodd ? u1.d[t] : u0.d[t];
            int rowbase = vd0 + (kodd ? 8 : 0);
            #pragma unroll
            for (int i = 0; i < 8; i++) {
                uint32_t m16 = (mine[i >> 1] >> ((i & 1) * 16)) & 0xffffu;
                uint32_t p16 = (recv[i >> 1] >> ((i & 1) * 16)) & 0xffffu;
                uint32_t word = kodd ? ((m16 << 16) | p16) : ((p16 << 16) | m16);
                *(uint32_t*)((char*)sVt + (size_t)(rowbase + i) * (LDK * 2) + keyLow * 2) = word;
            }
        }
        __syncthreads();

        // --- S = Q K^T + no-max softmax, P -> wave-private LDS ---
        for (int j = 0; j < 4; j++) {
            const bf16* kp = sK + (j * 16 + c15) * LDK + quad * 8;
            bf16x8 b0 = *(const bf16x8*)kp;
            bf16x8 b1 = *(const bf16x8*)(kp + 32);
            for (int i = 0; i < 2; i++) {
                floatx4 z = (floatx4){0.f, 0.f, 0.f, 0.f};
                z = __builtin_amdgcn_mfma_f32_16x16x32_bf16(aq[i][0], b0, z, 0, 0, 0);
                z = __builtin_amdgcn_mfma_f32_16x16x32_bf16(aq[i][1], b1, z, 0, 0, 0);
                #pragma unroll
                for (int r = 0; r < 4; r++) {
                    float p = exp2f(fminf(z[r], 120.f));   // q pre-scaled by log2e
                    lsum[i][r] += p;
                    sP[w][(i * 16 + quad * 4 + r) * LDK + j * 16 + c15] = (bf16)p;
                }
            }
        }

        // --- O += P V  (A = P rows, B = V^T rows; wave-private P, no barrier)
        bf16x8 ap[2][2];
        for (int i = 0; i < 2; i++) {
            const bf16* pp = &sP[w][(i * 16 + c15) * LDK + quad * 8];
            ap[i][0] = *(const bf16x8*)pp;
            ap[i][1] = *(const bf16x8*)(pp + 32);
        }
        for (int j = 0; j < 4; j++) {
            const bf16* vtp = sVt + (j * 16 + c15) * LDK + quad * 8;
            bf16x8 bv0 = *(const bf16x8*)vtp;
            bf16x8 bv1 = *(const bf16x8*)(vtp + 32);
            for (int i = 0; i < 2; i++) {
                o_acc[i][j] = __builtin_amdgcn_mfma_f32_16x16x32_bf16(ap[i][0], bv0, o_acc[i][j], 0, 0, 0);
                o_acc[i][j] = __builtin_amdgcn_mfma_f32_16x16x32_bf16(ap[i][1], bv1, o_acc[i][j], 0, 0, 0);
            }
        }
        __syncthreads();

        kptr += 64 * D_;
        vptr += 64 * D_;
    }

    // --- final l reduction (once per block) + epilogue ---
    for (int i = 0; i < 2; i++)
        for (int r = 0; r < 4; r++) {
            float s = lsum[i][r];
            s += __shfl_xor(s, 1, 64);
            s += __shfl_xor(s, 2, 64);
            s += __shfl_xor(s, 4, 64);
            s += __shfl_xor(s, 8, 64);
            lsum[i][r] = 1.0f / s;
        }
    for (int i = 0; i < 2; i++)
        for (int r = 0; r < 4; r++) {
            int row = n0 + w * 32 + i * 16 + quad * 4 + r;
            float* op = out + ((size_t)batch * N_ + row) * D_ + colOff;
            float inv = lsum[i][r];
            for (int j = 0; j < 4; j++) {
                float v = o_acc[i][j][r] * inv;
                int col = j * 16 + c15;
                if (accumulate) op[col] += v;
                else            op[col] = v;
            }
        }
}

// ---------------------------------------------------------------------------
extern "C" void kernel_launch(void* const* d_in, const int* in_sizes, int n_in,
                              void* d_out, int out_size, void* d_ws, size_t ws_size,
                              hipStream_t stream) {
    const float* x  = (const float*)d_in[0];
    const float* wq = (const float*)d_in[1];
    const float* bq = (const float*)d_in[2];
    const float* wk = (const float*)d_in[3];
    const float* bk = (const float*)d_in[4];
    const float* wv = (const float*)d_in[5];
    const float* bv = (const float*)d_in[6];
    float* out = (float*)d_out;

    // workspace layout (~61 MB total)
    char* ws = (char*)d_ws;
    bf16*  xbf = (bf16*)ws;                                   // 12,582,912 B
    bf16*  wbf = (bf16*)(ws + 12582912);                      // 10,616,832 B
    float* sc  = (float*)(ws + 12582912 + 10616832);          //     65,536 B
    bf16*  qkv = (bf16*)(ws + 12582912 + 10616832 + 65536);   // 37,748,736 B (one branch's q,k,v)

    hipLaunchKernelGGL(prep_x, dim3(M_), dim3(256), 0, stream, x, xbf, sc);
    hipLaunchKernelGGL(prep_w, dim3((9 * WSZ_ / 4) / 256), dim3(256), 0, stream, wq, wk, wv, wbf);
    for (int br = 0; br < 3; br++) {
        hipLaunchKernelGGL(gemm_qkv, dim3(D_ / BN, M_ / BM, 3), dim3(256), 0, stream,
                           xbf, wbf, bq, bk, bv, sc, br, qkv);
        hipLaunchKernelGGL(attn, dim3(N_ / 128, B_ * H_), dim3(256), 0, stream,
                           qkv, out, br);
    }
}